// Round 2
// baseline (249.793 us; speedup 1.0000x reference)
//
#include <hip/hip_runtime.h>

// M[t, i*768+p, j*768+q] = A[t,i,j] * exp(-maha - 0.5*logdet(D_tij)), row-normalized.
// D is 2x2 SPD -> closed-form inverse, coef = A * det^-1/2.
// Structure: ONE WAVE PER OUTPUT ROW-GROUP. Lane covers 24 cols interleaved as
// col = k*256 + lane*4 (k=0..5) -> every float4 store is lane-contiguous (1KB/instr).
// Row sum = in-register __shfl_xor butterfly: zero LDS, zero barriers.
// Each wave processes 4 rows of the same (t,i): S-points + both jj param sets
// loaded/computed once per 6144 outputs. Inputs fp32, output fp32.
//
// R5/R6: NONTEMPORAL output stores via native ext_vector_type (HIP float4 is a
// class -> builtin rejects it; clang vector works and emits global_store_dwordx4 nt).
// Output is 226.5 MB (7x L2), write-once, never re-read -> without nt, L2
// write-allocate + dirty eviction double-handles every line (kernel ran at
// ~2.4 TB/s effective vs 6.6 TB/s the poison fill proves reachable).
// Also: hoisted (sp - shift) per row/jj, pre-doubled a1 (saves 2 VALU/elem).

typedef unsigned int u32;
typedef float f32x4 __attribute__((ext_vector_type(4)));

namespace {
constexpr float GAMMA_C   = 0.3f;
constexpr float JITTER_C  = 1e-5f;
constexpr float ELL_MIN_C = 0.05f;
constexpr float ELL_MAX_C = 10.0f;
constexpr int   NPT     = 768;
constexpr int   TSTEPS  = 24;
constexpr int   ROWS    = TSTEPS * 2 * NPT;   // 36864
constexpr int   W_ROWS  = 4;                  // rows per wave
constexpr int   WAVES   = 4;                  // waves per block
constexpr int   THREADS = WAVES * 64;         // 256
constexpr int   RPB     = W_ROWS * WAVES;     // 16 rows per block
constexpr int   BLOCKS  = ROWS / RPB;         // 2304
}

__global__ __launch_bounds__(THREADS) void vlk_kernel(
    const float* __restrict__ S,         // [768,2]
    const float* __restrict__ mu_seq,    // [24,4]
    const float* __restrict__ Sg,        // [24,4,4]
    const float* __restrict__ A,         // [24,2,2]
    const float* __restrict__ rl,        // [2,2]
    float* __restrict__ out)             // [24,1536,1536]
{
    const int w    = threadIdx.x >> 6;
    const int lane = threadIdx.x & 63;

    const int base = blockIdx.x * RPB;          // first row of this block
    const int t    = base / (2 * NPT);
    const int rem  = base - t * (2 * NPT);
    const int i    = rem / NPT;                 // row-block index (uniform per block)
    const int p0   = rem - i * NPT + w * W_ROWS;

    // ---- per-(t,i) params for BOTH jj, once per wave-lifetime ----
    float mu[4];
#pragma unroll
    for (int k = 0; k < 4; ++k) mu[k] = mu_seq[t * 4 + k];
    float Sgm[4][4];
#pragma unroll
    for (int r = 0; r < 4; ++r)
#pragma unroll
        for (int c = 0; c < 4; ++c) Sgm[r][c] = Sg[t * 16 + r * 4 + c];

    float shift0[2], shift1[2], i00[2], i01x2[2], i11[2], coef[2];
    const int bi = 2 * i;
    const float g = GAMMA_C;
#pragma unroll
    for (int jj = 0; jj < 2; ++jj) {
        const int bj = 2 * jj;
        shift0[jj] = mu[bi]     - g * mu[bj];
        shift1[jj] = mu[bi + 1] - g * mu[bj + 1];
        const float b00 = Sgm[bi][bi]     - g*Sgm[bi][bj]     - g*Sgm[bj][bi]     + g*g*Sgm[bj][bj];
        const float b01 = Sgm[bi][bi+1]   - g*Sgm[bi][bj+1]   - g*Sgm[bj][bi+1]   + g*g*Sgm[bj][bj+1];
        const float b11 = Sgm[bi+1][bi+1] - g*Sgm[bi+1][bj+1] - g*Sgm[bj+1][bi+1] + g*g*Sgm[bj+1][bj+1];
        const float rlv = rl[i * 2 + jj];
        const float ell = ELL_MIN_C + (ELL_MAX_C - ELL_MIN_C) / (1.0f + __expf(-rlv));
        const float e2  = ell * ell + JITTER_C;
        const float D00 = e2 + 2.0f * b00;
        const float D01 =      2.0f * b01;
        const float D11 = e2 + 2.0f * b11;
        const float det  = D00 * D11 - D01 * D01;       // SPD -> det > 0
        const float rdet = 1.0f / det;
        i00[jj]   =  D11 * rdet;
        i01x2[jj] = -2.0f * D01 * rdet;                 // pre-doubled cross term
        i11[jj]   =  D00 * rdet;
        coef[jj] = A[(t * 2 + i) * 2 + jj] * rsqrtf(det);
    }

    // ---- S points for this lane's 12 q positions (shared by jj=0 and jj=1) ----
    // chunk m in 0..2: q = m*256 + lane*4 + {0..3}
    float sx[12], sy[12];
#pragma unroll
    for (int m = 0; m < 3; ++m) {
        const int q0 = m * 256 + lane * 4;
        const float4 a4 = *((const float4*)(S + 2 * q0));      // x0 y0 x1 y1
        const float4 b4 = *((const float4*)(S + 2 * q0 + 4));  // x2 y2 x3 y3
        sx[4*m+0] = a4.x; sy[4*m+0] = a4.y;
        sx[4*m+1] = a4.z; sy[4*m+1] = a4.w;
        sx[4*m+2] = b4.x; sy[4*m+2] = b4.y;
        sx[4*m+3] = b4.z; sy[4*m+3] = b4.w;
    }

    // ---- 4 rows per wave ----
#pragma unroll
    for (int r = 0; r < W_ROWS; ++r) {
        const int p = p0 + r;
        const float sp0 = S[2 * p];          // uniform per wave -> broadcast
        const float sp1 = S[2 * p + 1];

        // hoist (sp - shift) per jj: h = c - s[q]
        float cx[2], cy[2];
#pragma unroll
        for (int jj = 0; jj < 2; ++jj) {
            cx[jj] = sp0 - shift0[jj];
            cy[jj] = sp1 - shift1[jj];
        }

        float vals[24];
        float lsum = 0.0f;
#pragma unroll
        for (int k = 0; k < 6; ++k) {        // chunk: col = k*256 + lane*4
            const int jj = (k >= 3) ? 1 : 0;
            const int m  = k - 3 * jj;
            const float cx0 = cx[jj], cy0 = cy[jj];
            const float a0 = i00[jj], a1x2 = i01x2[jj], a2 = i11[jj], cf = coef[jj];
#pragma unroll
            for (int j = 0; j < 4; ++j) {
                const float h0 = cx0 - sx[4*m+j];
                const float h1 = cy0 - sy[4*m+j];
                const float maha = (a0 * h0 + a1x2 * h1) * h0 + a2 * h1 * h1;
                const float v = cf * __expf(-maha);
                vals[4*k+j] = v;
                lsum += v;
            }
        }

        // in-register wave reduction: all lanes end with the row total
#pragma unroll
        for (int off = 1; off < 64; off <<= 1) lsum += __shfl_xor(lsum, off, 64);
        const float inv = 1.0f / fmaxf(lsum, 1e-8f);    // clip(sum, 1e-8)

        float* op = out + (size_t)(base + w * W_ROWS + r) * (2 * NPT);
#pragma unroll
        for (int k = 0; k < 6; ++k) {
            f32x4 o;
            o.x = vals[4*k+0] * inv;
            o.y = vals[4*k+1] * inv;
            o.z = vals[4*k+2] * inv;
            o.w = vals[4*k+3] * inv;
            __builtin_nontemporal_store(o, (f32x4*)(op + k * 256 + lane * 4));
        }
    }
}

extern "C" void kernel_launch(void* const* d_in, const int* in_sizes, int n_in,
                              void* d_out, int out_size, void* d_ws, size_t ws_size,
                              hipStream_t stream) {
    vlk_kernel<<<BLOCKS, THREADS, 0, stream>>>(
        (const float*)d_in[0],   // S
        (const float*)d_in[1],   // mu_seq
        (const float*)d_in[2],   // Sigma_seq
        (const float*)d_in[3],   // A_seq
        (const float*)d_in[4],   // raw_ell
        (float*)d_out);
}

// Round 3
// 234.282 us; speedup vs baseline: 1.0662x; 1.0662x over previous
//
#include <hip/hip_runtime.h>

// M[t, i*768+p, j*768+q] = A[t,i,j] * exp(-maha - 0.5*logdet(D_tij)), row-normalized.
// D is 2x2 SPD -> closed-form inverse, coef = A * det^-1/2.
// Structure: ONE WAVE PER OUTPUT ROW-GROUP, PERSISTENT GRID-STRIDE.
// Lane covers 24 cols interleaved as col = k*256 + lane*4 (k=0..5) -> every
// float4 store is lane-contiguous (1KB/instr). Row sum = in-register
// __shfl_xor butterfly: zero LDS, zero barriers.
//
// R7: persistent waves. 768 blocks = 3 blocks/CU, each handling EXACTLY 3
// slots (2304 slots / 768) of 16 rows. Rationale: R2 showed nt stores are
// neutral (fill hits 6.6 TB/s through normal L2 path), so the kernel's ~2.4
// TB/s effective write BW is a wave-lifetime problem, not a cache-policy one:
// 2304 short-lived blocks -> 2.25 sequential generations/CU, each ending in a
// full vmcnt(0) drain + ragged tail. Grid-stride keeps stores streaming
// across 72 KB/wave and reuses the hoisted S-point registers 3x.
// Normal (cached) stores restored.

typedef unsigned int u32;

namespace {
constexpr float GAMMA_C   = 0.3f;
constexpr float JITTER_C  = 1e-5f;
constexpr float ELL_MIN_C = 0.05f;
constexpr float ELL_MAX_C = 10.0f;
constexpr int   NPT     = 768;
constexpr int   TSTEPS  = 24;
constexpr int   ROWS    = TSTEPS * 2 * NPT;   // 36864
constexpr int   W_ROWS  = 4;                  // rows per wave per slot
constexpr int   WAVES   = 4;                  // waves per block
constexpr int   THREADS = WAVES * 64;         // 256
constexpr int   RPB     = W_ROWS * WAVES;     // 16 rows per slot
constexpr int   SLOTS   = ROWS / RPB;         // 2304
constexpr int   BLOCKS  = 768;                // 3 slots per block exactly
}

__global__ __launch_bounds__(THREADS) void vlk_kernel(
    const float* __restrict__ S,         // [768,2]
    const float* __restrict__ mu_seq,    // [24,4]
    const float* __restrict__ Sg,        // [24,4,4]
    const float* __restrict__ A,         // [24,2,2]
    const float* __restrict__ rl,        // [2,2]
    float* __restrict__ out)             // [24,1536,1536]
{
    const int w    = threadIdx.x >> 6;
    const int lane = threadIdx.x & 63;

    // ---- S points for this lane's 12 q positions: invariant across slots ----
    // chunk m in 0..2: q = m*256 + lane*4 + {0..3}
    float sx[12], sy[12];
#pragma unroll
    for (int m = 0; m < 3; ++m) {
        const int q0 = m * 256 + lane * 4;
        const float4 a4 = *((const float4*)(S + 2 * q0));      // x0 y0 x1 y1
        const float4 b4 = *((const float4*)(S + 2 * q0 + 4));  // x2 y2 x3 y3
        sx[4*m+0] = a4.x; sy[4*m+0] = a4.y;
        sx[4*m+1] = a4.z; sy[4*m+1] = a4.w;
        sx[4*m+2] = b4.x; sy[4*m+2] = b4.y;
        sx[4*m+3] = b4.z; sy[4*m+3] = b4.w;
    }

    const float g = GAMMA_C;

    for (int slot = blockIdx.x; slot < SLOTS; slot += BLOCKS) {
        const int base = slot * RPB;                // first row of this slot
        const int t    = base / (2 * NPT);
        const int rem  = base - t * (2 * NPT);
        const int i    = rem / NPT;                 // row-block index (uniform)
        const int p0   = rem - i * NPT + w * W_ROWS;

        // ---- per-(t,i) params for BOTH jj ----
        float mu[4];
#pragma unroll
        for (int k = 0; k < 4; ++k) mu[k] = mu_seq[t * 4 + k];
        float Sgm[4][4];
#pragma unroll
        for (int r = 0; r < 4; ++r)
#pragma unroll
            for (int c = 0; c < 4; ++c) Sgm[r][c] = Sg[t * 16 + r * 4 + c];

        float shift0[2], shift1[2], i00[2], i01x2[2], i11[2], coef[2];
        const int bi = 2 * i;
#pragma unroll
        for (int jj = 0; jj < 2; ++jj) {
            const int bj = 2 * jj;
            shift0[jj] = mu[bi]     - g * mu[bj];
            shift1[jj] = mu[bi + 1] - g * mu[bj + 1];
            const float b00 = Sgm[bi][bi]     - g*Sgm[bi][bj]     - g*Sgm[bj][bi]     + g*g*Sgm[bj][bj];
            const float b01 = Sgm[bi][bi+1]   - g*Sgm[bi][bj+1]   - g*Sgm[bj][bi+1]   + g*g*Sgm[bj][bj+1];
            const float b11 = Sgm[bi+1][bi+1] - g*Sgm[bi+1][bj+1] - g*Sgm[bj+1][bi+1] + g*g*Sgm[bj+1][bj+1];
            const float rlv = rl[i * 2 + jj];
            const float ell = ELL_MIN_C + (ELL_MAX_C - ELL_MIN_C) / (1.0f + __expf(-rlv));
            const float e2  = ell * ell + JITTER_C;
            const float D00 = e2 + 2.0f * b00;
            const float D01 =      2.0f * b01;
            const float D11 = e2 + 2.0f * b11;
            const float det  = D00 * D11 - D01 * D01;       // SPD -> det > 0
            const float rdet = 1.0f / det;
            i00[jj]   =  D11 * rdet;
            i01x2[jj] = -2.0f * D01 * rdet;                 // pre-doubled cross term
            i11[jj]   =  D00 * rdet;
            coef[jj] = A[(t * 2 + i) * 2 + jj] * rsqrtf(det);
        }

        // ---- 4 rows per wave ----
#pragma unroll
        for (int r = 0; r < W_ROWS; ++r) {
            const int p = p0 + r;
            const float sp0 = S[2 * p];          // uniform per wave -> broadcast
            const float sp1 = S[2 * p + 1];

            float cx[2], cy[2];
#pragma unroll
            for (int jj = 0; jj < 2; ++jj) {
                cx[jj] = sp0 - shift0[jj];
                cy[jj] = sp1 - shift1[jj];
            }

            float vals[24];
            float lsum = 0.0f;
#pragma unroll
            for (int k = 0; k < 6; ++k) {        // chunk: col = k*256 + lane*4
                const int jj = (k >= 3) ? 1 : 0;
                const int m  = k - 3 * jj;
                const float cx0 = cx[jj], cy0 = cy[jj];
                const float a0 = i00[jj], a1x2 = i01x2[jj], a2 = i11[jj], cf = coef[jj];
#pragma unroll
                for (int j = 0; j < 4; ++j) {
                    const float h0 = cx0 - sx[4*m+j];
                    const float h1 = cy0 - sy[4*m+j];
                    const float maha = (a0 * h0 + a1x2 * h1) * h0 + a2 * h1 * h1;
                    const float v = cf * __expf(-maha);
                    vals[4*k+j] = v;
                    lsum += v;
                }
            }

            // in-register wave reduction: all lanes end with the row total
#pragma unroll
            for (int off = 1; off < 64; off <<= 1) lsum += __shfl_xor(lsum, off, 64);
            const float inv = 1.0f / fmaxf(lsum, 1e-8f);    // clip(sum, 1e-8)

            float* op = out + (size_t)(base + w * W_ROWS + r) * (2 * NPT);
#pragma unroll
            for (int k = 0; k < 6; ++k) {
                float4 o;
                o.x = vals[4*k+0] * inv;
                o.y = vals[4*k+1] * inv;
                o.z = vals[4*k+2] * inv;
                o.w = vals[4*k+3] * inv;
                *((float4*)(op + k * 256 + lane * 4)) = o;
            }
        }
    }
}

extern "C" void kernel_launch(void* const* d_in, const int* in_sizes, int n_in,
                              void* d_out, int out_size, void* d_ws, size_t ws_size,
                              hipStream_t stream) {
    vlk_kernel<<<BLOCKS, THREADS, 0, stream>>>(
        (const float*)d_in[0],   // S
        (const float*)d_in[1],   // mu_seq
        (const float*)d_in[2],   // Sigma_seq
        (const float*)d_in[3],   // A_seq
        (const float*)d_in[4],   // raw_ell
        (float*)d_out);
}